// Round 1
// baseline (83.764 us; speedup 1.0000x reference)
//
#include <hip/hip_runtime.h>
#include <hip/hip_bf16.h>

// Median blur 5x5, reflect padding, fp32, input (4,3,512,512).
// One thread per output pixel; 32x8 block; LDS halo tile 36x12.
// Median via 99-compare-exchange selection network (Smith/Devillard opt_med25),
// bit-exact lower median == median for odd count, NaN-free inputs.

#define TW 32
#define TH 8
#define PADR 2

__device__ __forceinline__ void ce(float& a, float& b) {
    float t = fminf(a, b);
    b = fmaxf(a, b);
    a = t;
}

__global__ __launch_bounds__(TW * TH) void median5_kernel(
    const float* __restrict__ in, float* __restrict__ out, int H, int W) {
    __shared__ float sm[TH + 2 * PADR][TW + 2 * PADR];  // 12 x 36

    const int plane = blockIdx.z;
    const float* ip = in + (size_t)plane * H * W;
    float* op = out + (size_t)plane * H * W;

    const int tx = threadIdx.x, ty = threadIdx.y;
    const int ox = blockIdx.x * TW, oy = blockIdx.y * TH;

    // Cooperative halo load: (TH+4)*(TW+4) = 432 elements, 256 threads.
    const int tid = ty * TW + tx;
    const int TILE_ELEMS = (TH + 4) * (TW + 4);
    for (int i = tid; i < TILE_ELEMS; i += TW * TH) {
        int r = i / (TW + 4);
        int c = i - r * (TW + 4);
        int gy = oy + r - PADR;
        int gx = ox + c - PADR;
        // reflect (mirror, no edge repeat); single reflection valid since pad=2 << 512
        gy = gy < 0 ? -gy : (gy >= H ? 2 * H - 2 - gy : gy);
        gx = gx < 0 ? -gx : (gx >= W ? 2 * W - 2 - gx : gx);
        sm[r][c] = ip[(size_t)gy * W + gx];
    }
    __syncthreads();

    float p[25];
#pragma unroll
    for (int dy = 0; dy < 5; ++dy)
#pragma unroll
        for (int dx = 0; dx < 5; ++dx)
            p[dy * 5 + dx] = sm[ty + dy][tx + dx];

    // Devillard opt_med25: 99 compare-exchanges, median lands in p[12].
    ce(p[0], p[1]); ce(p[3], p[4]); ce(p[2], p[4]);
    ce(p[2], p[3]); ce(p[6], p[7]); ce(p[5], p[7]);
    ce(p[5], p[6]); ce(p[9], p[10]); ce(p[8], p[10]);
    ce(p[8], p[9]); ce(p[12], p[13]); ce(p[11], p[13]);
    ce(p[11], p[12]); ce(p[15], p[16]); ce(p[14], p[16]);
    ce(p[14], p[15]); ce(p[18], p[19]); ce(p[17], p[19]);
    ce(p[17], p[18]); ce(p[21], p[22]); ce(p[20], p[22]);
    ce(p[20], p[21]); ce(p[23], p[24]); ce(p[2], p[5]);
    ce(p[3], p[6]); ce(p[0], p[6]); ce(p[0], p[3]);
    ce(p[4], p[7]); ce(p[1], p[7]); ce(p[1], p[4]);
    ce(p[11], p[14]); ce(p[8], p[14]); ce(p[8], p[11]);
    ce(p[12], p[15]); ce(p[9], p[15]); ce(p[9], p[12]);
    ce(p[13], p[16]); ce(p[10], p[16]); ce(p[10], p[13]);
    ce(p[20], p[23]); ce(p[17], p[23]); ce(p[17], p[20]);
    ce(p[21], p[24]); ce(p[18], p[24]); ce(p[18], p[21]);
    ce(p[19], p[22]); ce(p[8], p[17]); ce(p[9], p[18]);
    ce(p[0], p[18]); ce(p[0], p[9]); ce(p[10], p[19]);
    ce(p[1], p[19]); ce(p[1], p[10]); ce(p[11], p[20]);
    ce(p[2], p[20]); ce(p[2], p[11]); ce(p[12], p[21]);
    ce(p[3], p[21]); ce(p[3], p[12]); ce(p[13], p[22]);
    ce(p[4], p[22]); ce(p[4], p[13]); ce(p[14], p[23]);
    ce(p[5], p[23]); ce(p[5], p[14]); ce(p[15], p[24]);
    ce(p[6], p[24]); ce(p[6], p[15]); ce(p[7], p[16]);
    ce(p[7], p[19]); ce(p[13], p[21]); ce(p[15], p[23]);
    ce(p[7], p[13]); ce(p[7], p[15]); ce(p[1], p[9]);
    ce(p[3], p[11]); ce(p[5], p[17]); ce(p[11], p[17]);
    ce(p[9], p[17]); ce(p[4], p[10]); ce(p[6], p[12]);
    ce(p[7], p[14]); ce(p[4], p[6]); ce(p[4], p[7]);
    ce(p[12], p[14]); ce(p[10], p[14]); ce(p[6], p[7]);
    ce(p[10], p[12]); ce(p[6], p[10]); ce(p[6], p[17]);
    ce(p[12], p[17]); ce(p[7], p[17]); ce(p[7], p[10]);
    ce(p[12], p[18]); ce(p[7], p[12]); ce(p[10], p[18]);
    ce(p[12], p[20]); ce(p[10], p[20]); ce(p[10], p[12]);

    op[(size_t)(oy + ty) * W + (ox + tx)] = p[12];
}

extern "C" void kernel_launch(void* const* d_in, const int* in_sizes, int n_in,
                              void* d_out, int out_size, void* d_ws, size_t ws_size,
                              hipStream_t stream) {
    const float* img = (const float*)d_in[0];
    float* out = (float*)d_out;
    const int H = 512, W = 512;
    const int planes = in_sizes[0] / (H * W);  // 4*3 = 12
    dim3 block(TW, TH, 1);
    dim3 grid(W / TW, H / TH, planes);
    median5_kernel<<<grid, block, 0, stream>>>(img, out, H, W);
}

// Round 2
// 81.068 us; speedup vs baseline: 1.0333x; 1.0333x over previous
//
#include <hip/hip_runtime.h>
#include <hip/hip_bf16.h>

// Median blur 5x5, reflect pad, fp32, (4,3,512,512).
// v3: 4 pixels/thread along x, shared sorted columns, pruned order-statistic
// merge. Median of 25 = med of 13 doubly-sorted candidates, computed via
// exact order-stat formulas on sorted sub-lists (all hand-proven):
//   row0 top-2, row1 top-3, row2 mid-3, row3 bot-3, row4 bot-2,
//   then top2of4 / mid3of5 / bot2of4, then med3(max, med3, min).

#define TW 32
#define TH 8
#define PX 4
#define TILEW (TW * PX)   // 128
#define LDSW (TILEW + 4)  // 132
#define LDSH (TH + 4)     // 12

__device__ __forceinline__ float mn(float a, float b) { return fminf(a, b); }
__device__ __forceinline__ float mx(float a, float b) { return fmaxf(a, b); }
__device__ __forceinline__ float mn3(float a, float b, float c) { return fminf(a, fminf(b, c)); }
__device__ __forceinline__ float mx3(float a, float b, float c) { return fmaxf(a, fmaxf(b, c)); }
__device__ __forceinline__ float md3(float a, float b, float c) {
    return fmaxf(fminf(fmaxf(a, b), c), fminf(a, b));
}

// Full sort of 5 (ascending) via sort3 + sort2 + exact merge order stats.
__device__ __forceinline__ void sort5(float& v0, float& v1, float& v2, float& v3, float& v4) {
    float a1 = mn3(v0, v1, v2), a2 = md3(v0, v1, v2), a3 = mx3(v0, v1, v2);
    float b1 = mn(v3, v4), b2 = mx(v3, v4);
    float t1 = mx(a1, b1), u1 = mn(a2, b2), u2 = mn(a3, b2);
    float s0 = mn(a1, b1);
    float s1 = mn(t1, u1);
    float s2 = md3(a2, t1, u2);
    float s3 = mx(u2, mx(a2, b1));
    float s4 = mx(a3, b2);
    v0 = s0; v1 = s1; v2 = s2; v3 = s3; v4 = s4;
}

// ranks 2,3,4 of 5 arbitrary values (ascending o2<=o3<=o4)
__device__ __forceinline__ void top3of5(float v0, float v1, float v2, float v3, float v4,
                                        float& o2, float& o3, float& o4) {
    float a1 = mn3(v0, v1, v2), a2 = md3(v0, v1, v2), a3 = mx3(v0, v1, v2);
    float b1 = mn(v3, v4), b2 = mx(v3, v4);
    float t1 = mx(a1, b1), u2 = mn(a3, b2);
    o2 = md3(a2, t1, u2);
    o3 = mx(u2, mx(a2, b1));
    o4 = mx(a3, b2);
}

// ranks 1,2,3 of 5
__device__ __forceinline__ void mid3of5(float v0, float v1, float v2, float v3, float v4,
                                        float& o1, float& o2, float& o3) {
    float a1 = mn3(v0, v1, v2), a2 = md3(v0, v1, v2), a3 = mx3(v0, v1, v2);
    float b1 = mn(v3, v4), b2 = mx(v3, v4);
    float t1 = mx(a1, b1), u1 = mn(a2, b2), u2 = mn(a3, b2);
    o1 = mn(t1, u1);
    o2 = md3(a2, t1, u2);
    o3 = mx(u2, mx(a2, b1));
}

// ranks 0,1,2 of 5
__device__ __forceinline__ void bot3of5(float v0, float v1, float v2, float v3, float v4,
                                        float& o0, float& o1, float& o2) {
    float a1 = mn3(v0, v1, v2), a2 = md3(v0, v1, v2), a3 = mx3(v0, v1, v2);
    float b1 = mn(v3, v4), b2 = mx(v3, v4);
    float t1 = mx(a1, b1), u1 = mn(a2, b2), u2 = mn(a3, b2);
    o0 = mn(a1, b1);
    o1 = mn(t1, u1);
    o2 = md3(a2, t1, u2);
}

// ranks 3,4 of 5 (o3<=o4)
__device__ __forceinline__ void top2of5(float v0, float v1, float v2, float v3, float v4,
                                        float& o3, float& o4) {
    float p1 = mn(v0, v1), q1 = mx(v0, v1);
    float p2 = mn(v2, v3), q2 = mx(v2, v3);
    float xx2 = mx(q1, q2);
    float xx1 = mx3(p1, p2, mn(q1, q2));
    o4 = mx(xx2, v4);
    o3 = md3(xx1, xx2, v4);
}

// ranks 0,1 of 5
__device__ __forceinline__ void bot2of5(float v0, float v1, float v2, float v3, float v4,
                                        float& o0, float& o1) {
    float p1 = mn(v0, v1), q1 = mx(v0, v1);
    float p2 = mn(v2, v3), q2 = mx(v2, v3);
    float zz1 = mn(p1, p2);
    float zz2 = mn3(q1, q2, mx(p1, p2));
    o0 = mn(zz1, v4);
    o1 = md3(zz1, zz2, v4);
}

// ranks 2,3 of 4 (o2<=o3)
__device__ __forceinline__ void top2of4(float v0, float v1, float v2, float v3,
                                        float& o2, float& o3) {
    float p1 = mn(v0, v1), q1 = mx(v0, v1);
    float p2 = mn(v2, v3), q2 = mx(v2, v3);
    o3 = mx(q1, q2);
    o2 = mx3(p1, p2, mn(q1, q2));
}

// ranks 0,1 of 4
__device__ __forceinline__ void bot2of4(float v0, float v1, float v2, float v3,
                                        float& o0, float& o1) {
    float p1 = mn(v0, v1), q1 = mx(v0, v1);
    float p2 = mn(v2, v3), q2 = mx(v2, v3);
    o0 = mn(p1, p2);
    o1 = mn3(q1, q2, mx(p1, p2));
}

__global__ __launch_bounds__(TW * TH) void median5_kernel(
    const float* __restrict__ in, float* __restrict__ out, int H, int W) {
    __shared__ float sm[LDSH][LDSW];

    const int plane = blockIdx.z;
    const float* ip = in + (size_t)plane * H * W;
    float* op = out + (size_t)plane * H * W;

    const int tx = threadIdx.x, ty = threadIdx.y;
    const int ox = blockIdx.x * TILEW, oy = blockIdx.y * TH;
    const int tid = ty * TW + tx;

    for (int i = tid; i < LDSW * LDSH; i += TW * TH) {
        int rr = i / LDSW;
        int cc = i - rr * LDSW;
        int gy = oy + rr - 2;
        int gx = ox + cc - 2;
        gy = gy < 0 ? -gy : (gy >= H ? 2 * H - 2 - gy : gy);
        gx = gx < 0 ? -gx : (gx >= W ? 2 * W - 2 - gx : gx);
        sm[rr][cc] = ip[(size_t)gy * W + gx];
    }
    __syncthreads();

    // Load 8 columns x 5 rows into registers (two float4 per row, 16B aligned:
    // row stride 132 floats = 528 B = 33*16).
    float f[5][8];
#pragma unroll
    for (int dy = 0; dy < 5; ++dy) {
        float4 v0 = *(const float4*)&sm[ty + dy][tx * PX];
        float4 v1 = *(const float4*)&sm[ty + dy][tx * PX + 4];
        f[dy][0] = v0.x; f[dy][1] = v0.y; f[dy][2] = v0.z; f[dy][3] = v0.w;
        f[dy][4] = v1.x; f[dy][5] = v1.y; f[dy][6] = v1.z; f[dy][7] = v1.w;
    }

    // Sort each of the 8 columns along y (shared by the 4 output pixels).
#pragma unroll
    for (int c = 0; c < 8; ++c)
        sort5(f[0][c], f[1][c], f[2][c], f[3][c], f[4][c]);

    float res[4];
#pragma unroll
    for (int p = 0; p < 4; ++p) {
        // Rows of the col-sorted 5x5 window; keep only the 13 candidates.
        float a, b;
        top2of5(f[0][p], f[0][p + 1], f[0][p + 2], f[0][p + 3], f[0][p + 4], a, b);
        float c1, d1, e1;
        top3of5(f[1][p], f[1][p + 1], f[1][p + 2], f[1][p + 3], f[1][p + 4], c1, d1, e1);
        float f2, g2, h2;
        mid3of5(f[2][p], f[2][p + 1], f[2][p + 2], f[2][p + 3], f[2][p + 4], f2, g2, h2);
        float i3, j3, k3;
        bot3of5(f[3][p], f[3][p + 1], f[3][p + 2], f[3][p + 3], f[3][p + 4], i3, j3, k3);
        float l4, m4;
        bot2of5(f[4][p], f[4][p + 1], f[4][p + 2], f[4][p + 3], f[4][p + 4], l4, m4);

        // Second-level pruning (13 -> 7), then 3x3 closed form.
        float x1, x2;
        top2of4(a, c1, f2, i3, x1, x2);
        float y1, y2, y3;
        mid3of5(b, d1, g2, j3, l4, y1, y2, y3);
        float z1, z2;
        bot2of4(e1, h2, k3, m4, z1, z2);

        res[p] = md3(mx(x1, y1), md3(x2, y2, z1), mn(y3, z2));
    }

    float4 o;
    o.x = res[0]; o.y = res[1]; o.z = res[2]; o.w = res[3];
    *(float4*)&op[(size_t)(oy + ty) * W + ox + tx * PX] = o;
}

extern "C" void kernel_launch(void* const* d_in, const int* in_sizes, int n_in,
                              void* d_out, int out_size, void* d_ws, size_t ws_size,
                              hipStream_t stream) {
    const float* img = (const float*)d_in[0];
    float* out = (float*)d_out;
    const int H = 512, W = 512;
    const int planes = in_sizes[0] / (H * W);  // 12
    dim3 block(TW, TH, 1);
    dim3 grid(W / TILEW, H / TH, planes);
    median5_kernel<<<grid, block, 0, stream>>>(img, out, H, W);
}

// Round 3
// 78.787 us; speedup vs baseline: 1.0632x; 1.0290x over previous
//
#include <hip/hip_runtime.h>
#include <hip/hip_bf16.h>

// Median blur 5x5, reflect pad, fp32, (4,3,512,512).
// v4: 8 pixels/thread, shared sorted columns (12 sort5 per 8 px), pruned
// 13-candidate order-statistic merge, explicit v_med3_f32 via
// __builtin_amdgcn_fmed3f. Same proven order-stat logic as v3 (absmax 0).

#define TW 32
#define TH 8
#define PX 8
#define TILEW (TW * PX)   // 256
#define LDSW (TILEW + 4)  // 260  (row stride 1040 B = 65*16, float4-aligned)
#define LDSH (TH + 4)     // 12
#define NCOL (PX + 4)     // 12 columns per thread

__device__ __forceinline__ float mn(float a, float b) { return fminf(a, b); }
__device__ __forceinline__ float mx(float a, float b) { return fmaxf(a, b); }
__device__ __forceinline__ float mn3(float a, float b, float c) { return fminf(a, fminf(b, c)); }
__device__ __forceinline__ float mx3(float a, float b, float c) { return fmaxf(a, fmaxf(b, c)); }
__device__ __forceinline__ float md3(float a, float b, float c) {
    return __builtin_amdgcn_fmed3f(a, b, c);  // single v_med3_f32; NaN-free input
}

// Full sort of 5 (ascending): sort3 + sort2 + exact merge order stats.
__device__ __forceinline__ void sort5(float& v0, float& v1, float& v2, float& v3, float& v4) {
    float a1 = mn3(v0, v1, v2), a2 = md3(v0, v1, v2), a3 = mx3(v0, v1, v2);
    float b1 = mn(v3, v4), b2 = mx(v3, v4);
    float t1 = mx(a1, b1), u1 = mn(a2, b2), u2 = mn(a3, b2);
    float s0 = mn(a1, b1);
    float s1 = mn(t1, u1);
    float s2 = md3(a2, t1, u2);
    float s3 = mx(u2, mx(a2, b1));
    float s4 = mx(a3, b2);
    v0 = s0; v1 = s1; v2 = s2; v3 = s3; v4 = s4;
}

// ranks 2,3,4 of 5 (ascending o2<=o3<=o4)
__device__ __forceinline__ void top3of5(float v0, float v1, float v2, float v3, float v4,
                                        float& o2, float& o3, float& o4) {
    float a2 = md3(v0, v1, v2), a3 = mx3(v0, v1, v2);
    float a1 = mn3(v0, v1, v2);
    float b1 = mn(v3, v4), b2 = mx(v3, v4);
    float t1 = mx(a1, b1), u2 = mn(a3, b2);
    o2 = md3(a2, t1, u2);
    o3 = mx(u2, mx(a2, b1));
    o4 = mx(a3, b2);
}

// ranks 1,2,3 of 5
__device__ __forceinline__ void mid3of5(float v0, float v1, float v2, float v3, float v4,
                                        float& o1, float& o2, float& o3) {
    float a1 = mn3(v0, v1, v2), a2 = md3(v0, v1, v2), a3 = mx3(v0, v1, v2);
    float b1 = mn(v3, v4), b2 = mx(v3, v4);
    float t1 = mx(a1, b1), u1 = mn(a2, b2), u2 = mn(a3, b2);
    o1 = mn(t1, u1);
    o2 = md3(a2, t1, u2);
    o3 = mx(u2, mx(a2, b1));
}

// ranks 0,1,2 of 5
__device__ __forceinline__ void bot3of5(float v0, float v1, float v2, float v3, float v4,
                                        float& o0, float& o1, float& o2) {
    float a1 = mn3(v0, v1, v2), a2 = md3(v0, v1, v2), a3 = mx3(v0, v1, v2);
    float b1 = mn(v3, v4), b2 = mx(v3, v4);
    float t1 = mx(a1, b1), u1 = mn(a2, b2), u2 = mn(a3, b2);
    o0 = mn(a1, b1);
    o1 = mn(t1, u1);
    o2 = md3(a2, t1, u2);
}

// ranks 3,4 of 5 (o3<=o4)
__device__ __forceinline__ void top2of5(float v0, float v1, float v2, float v3, float v4,
                                        float& o3, float& o4) {
    float p1 = mn(v0, v1), q1 = mx(v0, v1);
    float p2 = mn(v2, v3), q2 = mx(v2, v3);
    float xx2 = mx(q1, q2);
    float xx1 = mx3(p1, p2, mn(q1, q2));
    o4 = mx(xx2, v4);
    o3 = md3(xx1, xx2, v4);
}

// ranks 0,1 of 5
__device__ __forceinline__ void bot2of5(float v0, float v1, float v2, float v3, float v4,
                                        float& o0, float& o1) {
    float p1 = mn(v0, v1), q1 = mx(v0, v1);
    float p2 = mn(v2, v3), q2 = mx(v2, v3);
    float zz1 = mn(p1, p2);
    float zz2 = mn3(q1, q2, mx(p1, p2));
    o0 = mn(zz1, v4);
    o1 = md3(zz1, zz2, v4);
}

// ranks 2,3 of 4 (o2<=o3)
__device__ __forceinline__ void top2of4(float v0, float v1, float v2, float v3,
                                        float& o2, float& o3) {
    float p1 = mn(v0, v1), q1 = mx(v0, v1);
    float p2 = mn(v2, v3), q2 = mx(v2, v3);
    o3 = mx(q1, q2);
    o2 = mx3(p1, p2, mn(q1, q2));
}

// ranks 0,1 of 4
__device__ __forceinline__ void bot2of4(float v0, float v1, float v2, float v3,
                                        float& o0, float& o1) {
    float p1 = mn(v0, v1), q1 = mx(v0, v1);
    float p2 = mn(v2, v3), q2 = mx(v2, v3);
    o0 = mn(p1, p2);
    o1 = mn3(q1, q2, mx(p1, p2));
}

__global__ __launch_bounds__(TW * TH) void median5_kernel(
    const float* __restrict__ in, float* __restrict__ out, int H, int W) {
    __shared__ float sm[LDSH][LDSW];

    const int plane = blockIdx.z;
    const float* ip = in + (size_t)plane * H * W;
    float* op = out + (size_t)plane * H * W;

    const int tx = threadIdx.x, ty = threadIdx.y;
    const int ox = blockIdx.x * TILEW, oy = blockIdx.y * TH;
    const int tid = ty * TW + tx;

    for (int i = tid; i < LDSW * LDSH; i += TW * TH) {
        int rr = i / LDSW;
        int cc = i - rr * LDSW;
        int gy = oy + rr - 2;
        int gx = ox + cc - 2;
        gy = gy < 0 ? -gy : (gy >= H ? 2 * H - 2 - gy : gy);
        gx = gx < 0 ? -gx : (gx >= W ? 2 * W - 2 - gx : gx);
        sm[rr][cc] = ip[(size_t)gy * W + gx];
    }
    __syncthreads();

    // 12 columns x 5 rows into registers (three float4 per row, 16B aligned).
    float f[5][NCOL];
#pragma unroll
    for (int dy = 0; dy < 5; ++dy) {
        const float4* base = (const float4*)&sm[ty + dy][tx * PX];
        float4 v0 = base[0], v1 = base[1], v2 = base[2];
        f[dy][0] = v0.x; f[dy][1] = v0.y; f[dy][2] = v0.z; f[dy][3] = v0.w;
        f[dy][4] = v1.x; f[dy][5] = v1.y; f[dy][6] = v1.z; f[dy][7] = v1.w;
        f[dy][8] = v2.x; f[dy][9] = v2.y; f[dy][10] = v2.z; f[dy][11] = v2.w;
    }

    // Sort the 12 columns along y (shared by the 8 output pixels).
#pragma unroll
    for (int c = 0; c < NCOL; ++c)
        sort5(f[0][c], f[1][c], f[2][c], f[3][c], f[4][c]);

    float res[PX];
#pragma unroll
    for (int p = 0; p < PX; ++p) {
        // 13 doubly-sorted candidates from the col-sorted 5x5 window.
        float a, b;
        top2of5(f[0][p], f[0][p + 1], f[0][p + 2], f[0][p + 3], f[0][p + 4], a, b);
        float c1, d1, e1;
        top3of5(f[1][p], f[1][p + 1], f[1][p + 2], f[1][p + 3], f[1][p + 4], c1, d1, e1);
        float f2, g2, h2;
        mid3of5(f[2][p], f[2][p + 1], f[2][p + 2], f[2][p + 3], f[2][p + 4], f2, g2, h2);
        float i3, j3, k3;
        bot3of5(f[3][p], f[3][p + 1], f[3][p + 2], f[3][p + 3], f[3][p + 4], i3, j3, k3);
        float l4, m4;
        bot2of5(f[4][p], f[4][p + 1], f[4][p + 2], f[4][p + 3], f[4][p + 4], l4, m4);

        // 13 -> 7 -> med3.
        float x1, x2;
        top2of4(a, c1, f2, i3, x1, x2);
        float y1, y2, y3;
        mid3of5(b, d1, g2, j3, l4, y1, y2, y3);
        float z1, z2;
        bot2of4(e1, h2, k3, m4, z1, z2);

        res[p] = md3(mx(x1, y1), md3(x2, y2, z1), mn(y3, z2));
    }

    // Two float4 stores (out row is 16B aligned at tx*PX*4).
    float4 o0, o1;
    o0.x = res[0]; o0.y = res[1]; o0.z = res[2]; o0.w = res[3];
    o1.x = res[4]; o1.y = res[5]; o1.z = res[6]; o1.w = res[7];
    float4* obase = (float4*)&op[(size_t)(oy + ty) * W + ox + tx * PX];
    obase[0] = o0;
    obase[1] = o1;
}

extern "C" void kernel_launch(void* const* d_in, const int* in_sizes, int n_in,
                              void* d_out, int out_size, void* d_ws, size_t ws_size,
                              hipStream_t stream) {
    const float* img = (const float*)d_in[0];
    float* out = (float*)d_out;
    const int H = 512, W = 512;
    const int planes = in_sizes[0] / (H * W);  // 12
    dim3 block(TW, TH, 1);
    dim3 grid(W / TILEW, H / TH, planes);
    median5_kernel<<<grid, block, 0, stream>>>(img, out, H, W);
}